// Round 1
// baseline (2386.325 us; speedup 1.0000x reference)
//
#include <hip/hip_runtime.h>
#include <math.h>

#define BB 4
#define NN 4096
#define DD 1024
#define TT (BB * NN)          // 16384 tokens
#define NC 64                 // scan chunks
#define CL (NN / NC)          // 64 steps per chunk

// ---------------------------------------------------------------------------
// Permute out_w (d, 2d) -> w2int (d, 2d) interleaved so that
// w2int[j][2k] = out_w[j][k], w2int[j][2k+1] = out_w[j][1024+k].
// Lets GEMM2 consume the (h_r,h_i)-interleaved feature directly.
// ---------------------------------------------------------------------------
__global__ __launch_bounds__(256) void permute_w2_kernel(
    const float* __restrict__ out_w, float* __restrict__ w2int) {
  int idx = blockIdx.x * 256 + threadIdx.x;   // over DD*2048
  int j = idx >> 11;
  int e = idx & 2047;
  int k = e >> 1;
  float v = (e & 1) ? out_w[(size_t)j * 2048 + 1024 + k]
                    : out_w[(size_t)j * 2048 + k];
  w2int[(size_t)j * 2048 + e] = v;
}

// ---------------------------------------------------------------------------
// GEMM1: proj[t][e] for e in [0,3072):
//   e < 2048 : gamma[e>>1] * (x_row . in_w[e] + in_b[e])      (= u interleaved)
//   e >= 2048: sigmoid(x_row . nu_w[e-2048] + nu_b[e-2048])   (= nu)
// token t -> x row (b = t&3, n = t>>2). 64x64 tile, BK=16, 4x4 per thread.
// ---------------------------------------------------------------------------
__global__ __launch_bounds__(256) void gemm1_kernel(
    const float* __restrict__ x,
    const float* __restrict__ in_w, const float* __restrict__ in_b,
    const float* __restrict__ nu_w, const float* __restrict__ nu_b,
    const float* __restrict__ gamma_log,
    float* __restrict__ proj) {
  __shared__ float As[16][68];
  __shared__ float Bs[16][68];
  const int tid = threadIdx.x;
  const int tile_m = blockIdx.y * 64;
  const int tile_n = blockIdx.x * 64;
  const int lr = tid >> 2;          // 0..63 row of tile for loading
  const int lk = (tid & 3) << 2;    // 0,4,8,12 k-offset
  const int tx = tid & 15;
  const int ty = tid >> 4;

  const int t = tile_m + lr;
  const float* arow = x + ((size_t)(t & 3) * NN + (t >> 2)) * DD;
  const int e = tile_n + lr;
  const float* brow = (e < 2048) ? (in_w + (size_t)e * DD)
                                 : (nu_w + (size_t)(e - 2048) * DD);
  float acc[4][4] = {};
  for (int k0 = 0; k0 < DD; k0 += 16) {
    float4 av = *(const float4*)(arow + k0 + lk);
    float4 bv = *(const float4*)(brow + k0 + lk);
    __syncthreads();
    As[lk + 0][lr] = av.x; As[lk + 1][lr] = av.y;
    As[lk + 2][lr] = av.z; As[lk + 3][lr] = av.w;
    Bs[lk + 0][lr] = bv.x; Bs[lk + 1][lr] = bv.y;
    Bs[lk + 2][lr] = bv.z; Bs[lk + 3][lr] = bv.w;
    __syncthreads();
#pragma unroll
    for (int kk = 0; kk < 16; ++kk) {
      float4 a4 = *(const float4*)&As[kk][ty << 2];
      float4 b4 = *(const float4*)&Bs[kk][tx << 2];
      float a[4] = {a4.x, a4.y, a4.z, a4.w};
      float b[4] = {b4.x, b4.y, b4.z, b4.w};
#pragma unroll
      for (int i = 0; i < 4; ++i)
#pragma unroll
        for (int j = 0; j < 4; ++j) acc[i][j] += a[i] * b[j];
    }
  }
  const bool is_in = (tile_n < 2048);   // block-uniform (2048 % 64 == 0)
#pragma unroll
  for (int j = 0; j < 4; ++j) {
    int ee = tile_n + (tx << 2) + j;
    float bias = is_in ? in_b[ee] : nu_b[ee - 2048];
    float gam = is_in ? expf(gamma_log[ee >> 1]) : 0.f;
#pragma unroll
    for (int i = 0; i < 4; ++i) {
      int tt = tile_m + (ty << 2) + i;
      float v = acc[i][j] + bias;
      v = is_in ? (gam * v) : (1.f / (1.f + expf(-v)));
      proj[(size_t)tt * 3072 + ee] = v;
    }
  }
}

// ---------------------------------------------------------------------------
// Scan phase 1: per (chunk c, batch b, channel dch), local scan from h=0.
// Emits (A_r, A_i, hend_r, hend_i) where A = prod of lambda over the chunk.
// ---------------------------------------------------------------------------
__global__ __launch_bounds__(256) void scan_p1_kernel(
    const float* __restrict__ proj,
    const float* __restrict__ theta_log,
    float* __restrict__ chunkA) {
  int s = blockIdx.x * 256 + threadIdx.x;   // ((c*BB)+b)*DD + dch
  int dch = s & (DD - 1);
  int b = (s >> 10) & (BB - 1);
  int c = s >> 12;
  float theta = expf(theta_log[dch]);
  float ct = cosf(theta), st = sinf(theta);
  float hr = 0.f, hi = 0.f, Ar = 1.f, Ai = 0.f;
  const float* base = proj + (size_t)(c * CL * BB + b) * 3072;
  for (int i = 0; i < CL; ++i) {
    const float* rowp = base + (size_t)i * (BB * 3072);
    float2 u = *(const float2*)(rowp + 2 * dch);
    float nu = rowp[2048 + dch];
    float lr = nu * ct, li = nu * st;
    float hr2 = lr * hr - li * hi + u.x;
    float hi2 = lr * hi + li * hr + u.y;
    hr = hr2; hi = hi2;
    float Ar2 = lr * Ar - li * Ai;
    float Ai2 = lr * Ai + li * Ar;
    Ar = Ar2; Ai = Ai2;
  }
  float4 o = {Ar, Ai, hr, hi};
  *(float4*)(chunkA + (size_t)s * 4) = o;
}

// ---------------------------------------------------------------------------
// Scan phase 2: sequentially compose the NC chunk summaries per channel,
// writing each chunk's carry-in state.
// ---------------------------------------------------------------------------
__global__ __launch_bounds__(256) void scan_p2_kernel(
    const float* __restrict__ chunkA,
    float* __restrict__ chunkInit) {
  int q = blockIdx.x * 256 + threadIdx.x;   // b*DD + dch
  int dch = q & (DD - 1);
  int b = q >> 10;
  float cr = 0.f, ci = 0.f;
  for (int c = 0; c < NC; ++c) {
    size_t idx = (size_t)(c * BB + b) * DD + dch;
    float4 v = *(const float4*)(chunkA + idx * 4);
    float2 w = {cr, ci};
    *(float2*)(chunkInit + idx * 2) = w;
    float nr = v.x * cr - v.y * ci + v.z;
    float ni = v.x * ci + v.y * cr + v.w;
    cr = nr; ci = ni;
  }
}

// ---------------------------------------------------------------------------
// Scan phase 3: re-run each chunk from its carry-in, overwriting the u-slots
// of proj with (h_r, h_i) interleaved -> feature for GEMM2.
// ---------------------------------------------------------------------------
__global__ __launch_bounds__(256) void scan_p3_kernel(
    float* __restrict__ proj,
    const float* __restrict__ theta_log,
    const float* __restrict__ chunkInit) {
  int s = blockIdx.x * 256 + threadIdx.x;
  int dch = s & (DD - 1);
  int b = (s >> 10) & (BB - 1);
  int c = s >> 12;
  float theta = expf(theta_log[dch]);
  float ct = cosf(theta), st = sinf(theta);
  float2 h0 = *(const float2*)(chunkInit + (size_t)s * 2);
  float hr = h0.x, hi = h0.y;
  float* base = proj + (size_t)(c * CL * BB + b) * 3072;
  for (int i = 0; i < CL; ++i) {
    float* rowp = base + (size_t)i * (BB * 3072);
    float2 u = *(const float2*)(rowp + 2 * dch);
    float nu = rowp[2048 + dch];
    float lr = nu * ct, li = nu * st;
    float hr2 = lr * hr - li * hi + u.x;
    float hi2 = lr * hi + li * hr + u.y;
    hr = hr2; hi = hi2;
    float2 h = {hr, hi};
    *(float2*)(rowp + 2 * dch) = h;
  }
}

// ---------------------------------------------------------------------------
// GEMM2: out[t][j] = feature[t][:2048] . w2int[j] + out_b[j]
// feature rows live in proj (stride 3072). Output mapping t -> (b,n,d).
// ---------------------------------------------------------------------------
__global__ __launch_bounds__(256) void gemm2_kernel(
    const float* __restrict__ proj,
    const float* __restrict__ w2int,
    const float* __restrict__ out_b,
    float* __restrict__ out) {
  __shared__ float As[16][68];
  __shared__ float Bs[16][68];
  const int tid = threadIdx.x;
  const int tile_m = blockIdx.y * 64;
  const int tile_n = blockIdx.x * 64;
  const int lr = tid >> 2;
  const int lk = (tid & 3) << 2;
  const int tx = tid & 15;
  const int ty = tid >> 4;

  const int t = tile_m + lr;
  const float* arow = proj + (size_t)t * 3072;
  const int j = tile_n + lr;
  const float* brow = w2int + (size_t)j * 2048;
  float acc[4][4] = {};
  for (int k0 = 0; k0 < 2048; k0 += 16) {
    float4 av = *(const float4*)(arow + k0 + lk);
    float4 bv = *(const float4*)(brow + k0 + lk);
    __syncthreads();
    As[lk + 0][lr] = av.x; As[lk + 1][lr] = av.y;
    As[lk + 2][lr] = av.z; As[lk + 3][lr] = av.w;
    Bs[lk + 0][lr] = bv.x; Bs[lk + 1][lr] = bv.y;
    Bs[lk + 2][lr] = bv.z; Bs[lk + 3][lr] = bv.w;
    __syncthreads();
#pragma unroll
    for (int kk = 0; kk < 16; ++kk) {
      float4 a4 = *(const float4*)&As[kk][ty << 2];
      float4 b4 = *(const float4*)&Bs[kk][tx << 2];
      float a[4] = {a4.x, a4.y, a4.z, a4.w};
      float b[4] = {b4.x, b4.y, b4.z, b4.w};
#pragma unroll
      for (int i = 0; i < 4; ++i)
#pragma unroll
        for (int jj = 0; jj < 4; ++jj) acc[i][jj] += a[i] * b[jj];
    }
  }
#pragma unroll
  for (int jj = 0; jj < 4; ++jj) {
    int col = tile_n + (tx << 2) + jj;
    float bias = out_b[col];
#pragma unroll
    for (int i = 0; i < 4; ++i) {
      int tt = tile_m + (ty << 2) + i;
      out[((size_t)(tt & 3) * NN + (tt >> 2)) * DD + col] = acc[i][jj] + bias;
    }
  }
}

extern "C" void kernel_launch(void* const* d_in, const int* in_sizes, int n_in,
                              void* d_out, int out_size, void* d_ws, size_t ws_size,
                              hipStream_t stream) {
  const float* x         = (const float*)d_in[0];
  const float* theta_log = (const float*)d_in[1];
  const float* gamma_log = (const float*)d_in[2];
  const float* nu_w      = (const float*)d_in[3];
  const float* nu_b      = (const float*)d_in[4];
  const float* in_w      = (const float*)d_in[5];
  const float* in_b      = (const float*)d_in[6];
  const float* out_w     = (const float*)d_in[7];
  const float* out_b     = (const float*)d_in[8];
  float* out = (float*)d_out;
  float* ws  = (float*)d_ws;

  // Workspace layout (floats):
  float* proj      = ws;                        // TT*3072      = 50,331,648
  float* w2int     = proj + (size_t)TT * 3072;  // DD*2048      =  2,097,152
  float* chunkA    = w2int + (size_t)DD * 2048; // NC*BB*DD*4   =  1,048,576
  float* chunkInit = chunkA + (size_t)NC * BB * DD * 4; // NC*BB*DD*2 = 524,288
  // total ~206 MiB

  permute_w2_kernel<<<(DD * 2048) / 256, 256, 0, stream>>>(out_w, w2int);
  gemm1_kernel<<<dim3(3072 / 64, TT / 64), 256, 0, stream>>>(
      x, in_w, in_b, nu_w, nu_b, gamma_log, proj);
  scan_p1_kernel<<<(NC * BB * DD) / 256, 256, 0, stream>>>(proj, theta_log, chunkA);
  scan_p2_kernel<<<(BB * DD) / 256, 256, 0, stream>>>(chunkA, chunkInit);
  scan_p3_kernel<<<(NC * BB * DD) / 256, 256, 0, stream>>>(proj, theta_log, chunkInit);
  gemm2_kernel<<<dim3(1024 / 64, TT / 64), 256, 0, stream>>>(proj, w2int, out_b, out);
}

// Round 3
// 599.110 us; speedup vs baseline: 3.9831x; 3.9831x over previous
//
#include <hip/hip_runtime.h>
#include <math.h>
#include <stdint.h>

#define BB 4
#define NN 4096
#define DD 1024
#define TT (BB * NN)          // 16384 tokens
#define NC 64                 // scan chunks
#define CL (NN / NC)          // 64 steps per chunk

typedef __attribute__((ext_vector_type(8))) short bf16x8;
typedef __attribute__((ext_vector_type(4))) float f32x4;

// bf16 round-to-nearest-even (returns top-16 bit pattern)
__device__ inline unsigned short bf_rne(float v) {
  union { float f; uint32_t u; } x; x.f = v;
  uint32_t r = x.u + 0x7fffu + ((x.u >> 16) & 1u);
  return (unsigned short)(r >> 16);
}

// async global->LDS, 16 bytes per lane, deposits at (wave-uniform base + lane*16)
__device__ inline void async16(const void* g, void* l) {
  __builtin_amdgcn_global_load_lds(
      (const __attribute__((address_space(1))) uint32_t*)g,
      (__attribute__((address_space(3))) uint32_t*)l, 16, 0, 0);
}

// ---------------------------------------------------------------------------
// conv_x: x (b,n,d) fp32 -> Abf (t = n*4+b, 1024) bf16
// ---------------------------------------------------------------------------
__global__ __launch_bounds__(256) void conv_x_kernel(
    const float* __restrict__ x, unsigned short* __restrict__ Abf) {
  int idx = blockIdx.x * 256 + threadIdx.x;     // over BB*NN*DD
  int k = idx & 1023;
  int n = (idx >> 10) & 4095;
  int b = idx >> 22;
  Abf[(size_t)(n * 4 + b) * 1024 + k] = bf_rne(x[idx]);
}

// ---------------------------------------------------------------------------
// conv_w1: rows [in_w(2048); nu_w(1024)] (e,1024) fp32 -> W1 bf16
// ---------------------------------------------------------------------------
__global__ __launch_bounds__(256) void conv_w1_kernel(
    const float* __restrict__ in_w, const float* __restrict__ nu_w,
    unsigned short* __restrict__ W1) {
  int idx = blockIdx.x * 256 + threadIdx.x;     // over 3072*1024
  float v = (idx < 2048 * 1024) ? in_w[idx] : nu_w[idx - 2048 * 1024];
  W1[idx] = bf_rne(v);
}

// ---------------------------------------------------------------------------
// conv_w2: out_w (j, 2048) fp32 -> W2 (j, 2048) bf16, (r,i)-interleaved:
// W2[j][2d] = out_w[j][d], W2[j][2d+1] = out_w[j][1024+d]
// ---------------------------------------------------------------------------
__global__ __launch_bounds__(256) void conv_w2_kernel(
    const float* __restrict__ out_w, unsigned short* __restrict__ W2) {
  int idx = blockIdx.x * 256 + threadIdx.x;     // over 1024*1024
  int j = idx >> 10, d = idx & 1023;
  W2[(size_t)j * 2048 + 2 * d]     = bf_rne(out_w[(size_t)j * 2048 + d]);
  W2[(size_t)j * 2048 + 2 * d + 1] = bf_rne(out_w[(size_t)j * 2048 + 1024 + d]);
}

// ---------------------------------------------------------------------------
// GEMM1 (MFMA): z = Abf[t,:] . W1[e,:], K=1024 bf16. 128x128 tile, BK=32,
// 4 waves, each 4x4 of 16x16x32 MFMA. Epilogue:
//   e < 2048 : U[t,e]   = gamma[e>>1]*(z + in_b[e])        (u interleaved)
//   e >= 2048: NU[t,e'] = fp16(sigmoid(z + nu_b[e']))
// ---------------------------------------------------------------------------
__global__ __launch_bounds__(256) void gemm1_mfma(
    const unsigned short* __restrict__ A,
    const unsigned short* __restrict__ W1,
    const float* __restrict__ in_b, const float* __restrict__ nu_b,
    const float* __restrict__ gamma_log,
    float* __restrict__ U, _Float16* __restrict__ NU) {
  __shared__ unsigned short As[4096];   // [kq=4][m=128][8] = 8 KB
  __shared__ unsigned short Bs[4096];
  const int tid = threadIdx.x;
  const int w = tid >> 6, l = tid & 63;
  const int q = l >> 4, ml = l & 15;
  const int m0 = blockIdx.y * 128;
  const int n0 = blockIdx.x * 128;
  const int wm = w & 1, wn = w >> 1;

  f32x4 acc[4][4] = {};

  for (int k0 = 0; k0 < 1024; k0 += 32) {
    __syncthreads();
    async16(A + (size_t)(m0 + l) * 1024 + k0 + w * 8, &As[(w * 128) * 8]);
    async16(A + (size_t)(m0 + 64 + l) * 1024 + k0 + w * 8, &As[(w * 128 + 64) * 8]);
    async16(W1 + (size_t)(n0 + l) * 1024 + k0 + w * 8, &Bs[(w * 128) * 8]);
    async16(W1 + (size_t)(n0 + 64 + l) * 1024 + k0 + w * 8, &Bs[(w * 128 + 64) * 8]);
    __syncthreads();
    bf16x8 af[4], bfr[4];
#pragma unroll
    for (int i = 0; i < 4; ++i)
      af[i] = *(const bf16x8*)&As[(q * 128 + wm * 64 + i * 16 + ml) * 8];
#pragma unroll
    for (int j = 0; j < 4; ++j)
      bfr[j] = *(const bf16x8*)&Bs[(q * 128 + wn * 64 + j * 16 + ml) * 8];
#pragma unroll
    for (int i = 0; i < 4; ++i)
#pragma unroll
      for (int j = 0; j < 4; ++j)
        acc[i][j] = __builtin_amdgcn_mfma_f32_16x16x32_bf16(af[i], bfr[j], acc[i][j], 0, 0, 0);
  }

  if (n0 < 2048) {   // u columns (block-uniform)
#pragma unroll
    for (int j = 0; j < 4; ++j) {
      int col = n0 + wn * 64 + j * 16 + ml;
      float bias = in_b[col];
      float gam = expf(gamma_log[col >> 1]);
#pragma unroll
      for (int i = 0; i < 4; ++i) {
        int trow = m0 + wm * 64 + i * 16 + q * 4;
#pragma unroll
        for (int v = 0; v < 4; ++v)
          U[(size_t)(trow + v) * 2048 + col] = gam * (acc[i][j][v] + bias);
      }
    }
  } else {           // nu columns
#pragma unroll
    for (int j = 0; j < 4; ++j) {
      int col = n0 + wn * 64 + j * 16 + ml;
      int c2 = col - 2048;
      float bias = nu_b[c2];
#pragma unroll
      for (int i = 0; i < 4; ++i) {
        int trow = m0 + wm * 64 + i * 16 + q * 4;
#pragma unroll
        for (int v = 0; v < 4; ++v) {
          float z = acc[i][j][v] + bias;
          NU[(size_t)(trow + v) * 1024 + c2] = (_Float16)(1.f / (1.f + expf(-z)));
        }
      }
    }
  }
}

// ---------------------------------------------------------------------------
// Scan phase 1: per (chunk c, batch b, channel dch) local scan from h=0.
// Emits (A_r, A_i, hend_r, hend_i), A = prod of lambda over the chunk.
// ---------------------------------------------------------------------------
__global__ __launch_bounds__(256) void scan_p1_kernel(
    const float* __restrict__ U, const _Float16* __restrict__ NU,
    const float* __restrict__ theta_log,
    float* __restrict__ chunkA) {
  int s = blockIdx.x * 256 + threadIdx.x;   // ((c*BB)+b)*DD + dch
  int dch = s & (DD - 1);
  int b = (s >> 10) & (BB - 1);
  int c = s >> 12;
  float theta = expf(theta_log[dch]);
  float ct = cosf(theta), st = sinf(theta);
  float hr = 0.f, hi = 0.f, Ar = 1.f, Ai = 0.f;
  for (int i = 0; i < CL; ++i) {
    int t = (c * CL + i) * 4 + b;
    float2 u = *(const float2*)(U + (size_t)t * 2048 + 2 * dch);
    float nu = (float)NU[(size_t)t * 1024 + dch];
    float lr = nu * ct, li = nu * st;
    float hr2 = lr * hr - li * hi + u.x;
    float hi2 = lr * hi + li * hr + u.y;
    hr = hr2; hi = hi2;
    float Ar2 = lr * Ar - li * Ai;
    float Ai2 = lr * Ai + li * Ar;
    Ar = Ar2; Ai = Ai2;
  }
  float4 o = {Ar, Ai, hr, hi};
  *(float4*)(chunkA + (size_t)s * 4) = o;
}

// ---------------------------------------------------------------------------
// Scan phase 2: compose NC chunk summaries per channel; overwrite each
// entry's (z,w) slots in-place with that chunk's carry-in state.
// ---------------------------------------------------------------------------
__global__ __launch_bounds__(256) void scan_p2_kernel(
    float* __restrict__ chunkA) {
  int qx = blockIdx.x * 256 + threadIdx.x;   // b*DD + dch
  int dch = qx & (DD - 1);
  int b = qx >> 10;
  float cr = 0.f, ci = 0.f;
  for (int c = 0; c < NC; ++c) {
    size_t idx = ((size_t)(c * BB + b) * DD + dch) * 4;
    float4 v = *(const float4*)(chunkA + idx);
    float2 wv = {cr, ci};
    *(float2*)(chunkA + idx + 2) = wv;      // carry-in for chunk c
    float nr = v.x * cr - v.y * ci + v.z;
    float ni = v.x * ci + v.y * cr + v.w;
    cr = nr; ci = ni;
  }
}

// ---------------------------------------------------------------------------
// Scan phase 3: block per (c,b); re-run chunk from carry-in; write feature
// bf16 pairs IN-PLACE into the head of each U row:
//   F[t] = shorts [0,2048) of U row t, F[t][2d]=bf16(h_r[d]), [2d+1]=bf16(h_i[d])
// One __syncthreads per step separates all-reads (bytes 32*tid..) from
// all-writes (bytes 16*tid..) of the same row.
// ---------------------------------------------------------------------------
__global__ __launch_bounds__(256) void scan_p3_kernel(
    float* __restrict__ U, const _Float16* __restrict__ NU,
    const float* __restrict__ theta_log, const float* __restrict__ chunkA) {
  const int c = blockIdx.x >> 2, b = blockIdx.x & 3;
  const int tid = threadIdx.x;
  float ct[4], st[4], hr[4], hi_[4];
#pragma unroll
  for (int dj = 0; dj < 4; ++dj) {
    int d = tid * 4 + dj;
    float th = expf(theta_log[d]);
    ct[dj] = cosf(th); st[dj] = sinf(th);
    const float* cp = chunkA + ((size_t)((c * 4 + b) * 1024) + d) * 4 + 2;
    hr[dj] = cp[0]; hi_[dj] = cp[1];
  }
  for (int i = 0; i < CL; ++i) {
    int t = (c * CL + i) * 4 + b;
    float* urow = U + (size_t)t * 2048;
    float4 ua = *(const float4*)(urow + 8 * tid);
    float4 ub = *(const float4*)(urow + 8 * tid + 4);
    float uu[8] = {ua.x, ua.y, ua.z, ua.w, ub.x, ub.y, ub.z, ub.w};
    const _Float16* nup = NU + (size_t)t * 1024 + 4 * tid;
    unsigned short fo[8];
#pragma unroll
    for (int dj = 0; dj < 4; ++dj) {
      float nu = (float)nup[dj];
      float lr = nu * ct[dj], li = nu * st[dj];
      float nhr = lr * hr[dj] - li * hi_[dj] + uu[2 * dj];
      float nhi = lr * hi_[dj] + li * hr[dj] + uu[2 * dj + 1];
      hr[dj] = nhr; hi_[dj] = nhi;
      fo[2 * dj] = bf_rne(nhr);
      fo[2 * dj + 1] = bf_rne(nhi);
    }
    __syncthreads();
    *(bf16x8*)((unsigned short*)urow + 8 * tid) = *(const bf16x8*)fo;
  }
}

// ---------------------------------------------------------------------------
// GEMM2 (MFMA): out[t][j] = F[t,:] . W2[j,:] + out_b[j], K=2048 bf16.
// F rows live at the head of U rows (row stride 4096 shorts).
// ---------------------------------------------------------------------------
__global__ __launch_bounds__(256) void gemm2_mfma(
    const unsigned short* __restrict__ F,      // stride 4096, first 2048 valid
    const unsigned short* __restrict__ W2,
    const float* __restrict__ out_b,
    float* __restrict__ out) {
  __shared__ unsigned short As[4096];
  __shared__ unsigned short Bs[4096];
  const int tid = threadIdx.x;
  const int w = tid >> 6, l = tid & 63;
  const int q = l >> 4, ml = l & 15;
  const int m0 = blockIdx.y * 128;
  const int n0 = blockIdx.x * 128;
  const int wm = w & 1, wn = w >> 1;

  f32x4 acc[4][4] = {};

  for (int k0 = 0; k0 < 2048; k0 += 32) {
    __syncthreads();
    async16(F + (size_t)(m0 + l) * 4096 + k0 + w * 8, &As[(w * 128) * 8]);
    async16(F + (size_t)(m0 + 64 + l) * 4096 + k0 + w * 8, &As[(w * 128 + 64) * 8]);
    async16(W2 + (size_t)(n0 + l) * 2048 + k0 + w * 8, &Bs[(w * 128) * 8]);
    async16(W2 + (size_t)(n0 + 64 + l) * 2048 + k0 + w * 8, &Bs[(w * 128 + 64) * 8]);
    __syncthreads();
    bf16x8 af[4], bfr[4];
#pragma unroll
    for (int i = 0; i < 4; ++i)
      af[i] = *(const bf16x8*)&As[(q * 128 + wm * 64 + i * 16 + ml) * 8];
#pragma unroll
    for (int j = 0; j < 4; ++j)
      bfr[j] = *(const bf16x8*)&Bs[(q * 128 + wn * 64 + j * 16 + ml) * 8];
#pragma unroll
    for (int i = 0; i < 4; ++i)
#pragma unroll
      for (int j = 0; j < 4; ++j)
        acc[i][j] = __builtin_amdgcn_mfma_f32_16x16x32_bf16(af[i], bfr[j], acc[i][j], 0, 0, 0);
  }

#pragma unroll
  for (int j = 0; j < 4; ++j) {
    int col = n0 + wn * 64 + j * 16 + ml;
    float bias = out_b[col];
#pragma unroll
    for (int i = 0; i < 4; ++i) {
      int trow = m0 + wm * 64 + i * 16 + q * 4;
#pragma unroll
      for (int v = 0; v < 4; ++v) {
        int t = trow + v;
        out[((size_t)(t & 3) * NN + (t >> 2)) * DD + col] = acc[i][j][v] + bias;
      }
    }
  }
}

extern "C" void kernel_launch(void* const* d_in, const int* in_sizes, int n_in,
                              void* d_out, int out_size, void* d_ws, size_t ws_size,
                              hipStream_t stream) {
  const float* x         = (const float*)d_in[0];
  const float* theta_log = (const float*)d_in[1];
  const float* gamma_log = (const float*)d_in[2];
  const float* nu_w      = (const float*)d_in[3];
  const float* nu_b      = (const float*)d_in[4];
  const float* in_w      = (const float*)d_in[5];
  const float* in_b      = (const float*)d_in[6];
  const float* out_w     = (const float*)d_in[7];
  const float* out_b     = (const float*)d_in[8];
  float* out = (float*)d_out;

  // Workspace layout (211,812,352 B total; round 0 proved ws_size >= 216 MB):
  char* base = (char*)d_ws;
  float*          U   = (float*)base;                          // 134,217,728
  _Float16*       NU  = (_Float16*)(base + 134217728);         //  33,554,432
  unsigned short* Abf = (unsigned short*)(base + 167772160);   //  33,554,432
  unsigned short* W1  = (unsigned short*)(base + 201326592);   //   6,291,456
  unsigned short* W2  = (unsigned short*)(base + 167772160);   //   4,194,304 (over dead Abf)
  float*          chunkA = (float*)(base + 207618048);         //   4,194,304

  conv_x_kernel<<<(BB * NN * DD) / 256, 256, 0, stream>>>(x, Abf);
  conv_w1_kernel<<<(3072 * 1024) / 256, 256, 0, stream>>>(in_w, nu_w, W1);
  gemm1_mfma<<<dim3(3072 / 128, TT / 128), 256, 0, stream>>>(
      Abf, W1, in_b, nu_b, gamma_log, U, NU);
  conv_w2_kernel<<<(1024 * 1024) / 256, 256, 0, stream>>>(out_w, W2);  // Abf dead now
  scan_p1_kernel<<<(NC * BB * DD) / 256, 256, 0, stream>>>(U, NU, theta_log, chunkA);
  scan_p2_kernel<<<(BB * DD) / 256, 256, 0, stream>>>(chunkA);
  scan_p3_kernel<<<NC * BB, 256, 0, stream>>>(U, NU, theta_log, chunkA);
  gemm2_mfma<<<dim3(1024 / 128, TT / 128), 256, 0, stream>>>(
      (const unsigned short*)U, W2, out_b, out);
}

// Round 4
// 566.937 us; speedup vs baseline: 4.2092x; 1.0567x over previous
//
#include <hip/hip_runtime.h>
#include <math.h>
#include <stdint.h>

#define BB 4
#define NN 4096
#define DD 1024
#define TT (BB * NN)          // 16384 tokens
#define NC 64                 // scan chunks
#define CL (NN / NC)          // 64 steps per chunk

typedef __attribute__((ext_vector_type(8))) short bf16x8;
typedef __attribute__((ext_vector_type(4))) float f32x4;

// bf16 round-to-nearest-even (returns top-16 bit pattern)
__device__ inline unsigned short bf_rne(float v) {
  union { float f; uint32_t u; } x; x.f = v;
  uint32_t r = x.u + 0x7fffu + ((x.u >> 16) & 1u);
  return (unsigned short)(r >> 16);
}
__device__ inline float bf_to_f(unsigned short h) {
  union { float f; uint32_t u; } x; x.u = ((uint32_t)h) << 16;
  return x.f;
}

// async global->LDS, 16 bytes per lane, deposits at (wave-uniform base + lane*16)
__device__ inline void async16(const void* g, void* l) {
  __builtin_amdgcn_global_load_lds(
      (const __attribute__((address_space(1))) uint32_t*)g,
      (__attribute__((address_space(3))) uint32_t*)l, 16, 0, 0);
}

// ---------------------------------------------------------------------------
// conv_x: x (b,n,d) fp32 -> Abf (t = n*4+b, 1024) bf16
// ---------------------------------------------------------------------------
__global__ __launch_bounds__(256) void conv_x_kernel(
    const float* __restrict__ x, unsigned short* __restrict__ Abf) {
  int idx = blockIdx.x * 256 + threadIdx.x;     // over BB*NN*DD
  int k = idx & 1023;
  int n = (idx >> 10) & 4095;
  int b = idx >> 22;
  Abf[(size_t)(n * 4 + b) * 1024 + k] = bf_rne(x[idx]);
}

// ---------------------------------------------------------------------------
// conv_w1: rows [in_w(2048); nu_w(1024)] (e,1024) fp32 -> W1 bf16
// ---------------------------------------------------------------------------
__global__ __launch_bounds__(256) void conv_w1_kernel(
    const float* __restrict__ in_w, const float* __restrict__ nu_w,
    unsigned short* __restrict__ W1) {
  int idx = blockIdx.x * 256 + threadIdx.x;     // over 3072*1024
  float v = (idx < 2048 * 1024) ? in_w[idx] : nu_w[idx - 2048 * 1024];
  W1[idx] = bf_rne(v);
}

// ---------------------------------------------------------------------------
// conv_w2: out_w (j, 2048) fp32 -> W2 (j, 2048) bf16, (r,i)-interleaved:
// W2[j][2d] = out_w[j][d], W2[j][2d+1] = out_w[j][1024+d]
// ---------------------------------------------------------------------------
__global__ __launch_bounds__(256) void conv_w2_kernel(
    const float* __restrict__ out_w, unsigned short* __restrict__ W2) {
  int idx = blockIdx.x * 256 + threadIdx.x;     // over 1024*1024
  int j = idx >> 10, d = idx & 1023;
  W2[(size_t)j * 2048 + 2 * d]     = bf_rne(out_w[(size_t)j * 2048 + d]);
  W2[(size_t)j * 2048 + 2 * d + 1] = bf_rne(out_w[(size_t)j * 2048 + 1024 + d]);
}

// ---------------------------------------------------------------------------
// GEMM1 (MFMA): z = Abf[t,:] . W1[e,:], K=1024 bf16. 128x128 tile, BK=64
// (16 K-iters, 32 MFMA per barrier), 4 waves, each 4x4 of 16x16x32 MFMA.
// Epilogue:
//   e < 2048 : U16[t,e]  = bf16( gamma[e>>1]*(z + in_b[e]) )   (u interleaved)
//   e >= 2048: NU[t,e']  = fp16( sigmoid(z + nu_b[e']) )
// LDS layout [kq=8][m=128][8]: conflict-free ds_read_b128, matches the
// global_load_lds wave-uniform-base + lane*16 deposit rule.
// ---------------------------------------------------------------------------
__global__ __launch_bounds__(256) void gemm1_mfma(
    const unsigned short* __restrict__ A,
    const unsigned short* __restrict__ W1,
    const float* __restrict__ in_b, const float* __restrict__ nu_b,
    const float* __restrict__ gamma_log,
    unsigned short* __restrict__ U16, _Float16* __restrict__ NU) {
  __shared__ unsigned short As[8192];   // 16 KB
  __shared__ unsigned short Bs[8192];   // 16 KB
  const int tid = threadIdx.x;
  const int w = tid >> 6, l = tid & 63;
  const int q = l >> 4, ml = l & 15;
  const int m0 = blockIdx.y * 128;
  const int n0 = blockIdx.x * 128;
  const int wm = w & 1, wn = w >> 1;

  f32x4 acc[4][4] = {};

  for (int k0 = 0; k0 < 1024; k0 += 64) {
    __syncthreads();
#pragma unroll
    for (int h = 0; h < 2; ++h) {
      int kq = 2 * w + h;     // wave w stages kq slices 2w, 2w+1
      async16(A + (size_t)(m0 + l) * 1024 + k0 + kq * 8, &As[(kq * 128) * 8]);
      async16(A + (size_t)(m0 + 64 + l) * 1024 + k0 + kq * 8, &As[(kq * 128 + 64) * 8]);
      async16(W1 + (size_t)(n0 + l) * 1024 + k0 + kq * 8, &Bs[(kq * 128) * 8]);
      async16(W1 + (size_t)(n0 + 64 + l) * 1024 + k0 + kq * 8, &Bs[(kq * 128 + 64) * 8]);
    }
    __syncthreads();
#pragma unroll
    for (int s = 0; s < 2; ++s) {
      bf16x8 af[4], bfr[4];
#pragma unroll
      for (int i = 0; i < 4; ++i)
        af[i] = *(const bf16x8*)&As[(((s * 4 + q) * 128) + wm * 64 + i * 16 + ml) * 8];
#pragma unroll
      for (int j = 0; j < 4; ++j)
        bfr[j] = *(const bf16x8*)&Bs[(((s * 4 + q) * 128) + wn * 64 + j * 16 + ml) * 8];
#pragma unroll
      for (int i = 0; i < 4; ++i)
#pragma unroll
        for (int j = 0; j < 4; ++j)
          acc[i][j] = __builtin_amdgcn_mfma_f32_16x16x32_bf16(af[i], bfr[j], acc[i][j], 0, 0, 0);
    }
  }

  if (n0 < 2048) {   // u columns (block-uniform)
#pragma unroll
    for (int j = 0; j < 4; ++j) {
      int col = n0 + wn * 64 + j * 16 + ml;
      float bias = in_b[col];
      float gam = expf(gamma_log[col >> 1]);
#pragma unroll
      for (int i = 0; i < 4; ++i) {
        int trow = m0 + wm * 64 + i * 16 + q * 4;
#pragma unroll
        for (int v = 0; v < 4; ++v)
          U16[(size_t)(trow + v) * 2048 + col] = bf_rne(gam * (acc[i][j][v] + bias));
      }
    }
  } else {           // nu columns
#pragma unroll
    for (int j = 0; j < 4; ++j) {
      int col = n0 + wn * 64 + j * 16 + ml;
      int c2 = col - 2048;
      float bias = nu_b[c2];
#pragma unroll
      for (int i = 0; i < 4; ++i) {
        int trow = m0 + wm * 64 + i * 16 + q * 4;
#pragma unroll
        for (int v = 0; v < 4; ++v) {
          float z = acc[i][j][v] + bias;
          NU[(size_t)(trow + v) * 1024 + c2] = (_Float16)(1.f / (1.f + expf(-z)));
        }
      }
    }
  }
}

// ---------------------------------------------------------------------------
// Scan phase 1: per (chunk c, batch b, channel dch) local scan from h=0.
// Emits (A_r, A_i, hend_r, hend_i), A = prod of lambda over the chunk.
// ---------------------------------------------------------------------------
__global__ __launch_bounds__(256) void scan_p1_kernel(
    const unsigned short* __restrict__ U16, const _Float16* __restrict__ NU,
    const float* __restrict__ theta_log,
    float* __restrict__ chunkA) {
  int s = blockIdx.x * 256 + threadIdx.x;   // ((c*BB)+b)*DD + dch
  int dch = s & (DD - 1);
  int b = (s >> 10) & (BB - 1);
  int c = s >> 12;
  float theta = expf(theta_log[dch]);
  float ct = cosf(theta), st = sinf(theta);
  float hr = 0.f, hi = 0.f, Ar = 1.f, Ai = 0.f;
  for (int i = 0; i < CL; ++i) {
    int t = (c * CL + i) * 4 + b;
    ushort2 up = *(const ushort2*)(U16 + (size_t)t * 2048 + 2 * dch);
    float ur = bf_to_f(up.x), ui = bf_to_f(up.y);
    float nu = (float)NU[(size_t)t * 1024 + dch];
    float lr = nu * ct, li = nu * st;
    float hr2 = lr * hr - li * hi + ur;
    float hi2 = lr * hi + li * hr + ui;
    hr = hr2; hi = hi2;
    float Ar2 = lr * Ar - li * Ai;
    float Ai2 = lr * Ai + li * Ar;
    Ar = Ar2; Ai = Ai2;
  }
  float4 o = {Ar, Ai, hr, hi};
  *(float4*)(chunkA + (size_t)s * 4) = o;
}

// ---------------------------------------------------------------------------
// Scan phase 2: compose NC chunk summaries per channel; overwrite each
// entry's (z,w) slots in-place with that chunk's carry-in state.
// ---------------------------------------------------------------------------
__global__ __launch_bounds__(256) void scan_p2_kernel(
    float* __restrict__ chunkA) {
  int qx = blockIdx.x * 256 + threadIdx.x;   // b*DD + dch
  int dch = qx & (DD - 1);
  int b = qx >> 10;
  float cr = 0.f, ci = 0.f;
  for (int c = 0; c < NC; ++c) {
    size_t idx = ((size_t)(c * BB + b) * DD + dch) * 4;
    float4 v = *(const float4*)(chunkA + idx);
    float2 wv = {cr, ci};
    *(float2*)(chunkA + idx + 2) = wv;      // carry-in for chunk c
    float nr = v.x * cr - v.y * ci + v.z;
    float ni = v.x * ci + v.y * cr + v.w;
    cr = nr; ci = ni;
  }
}

// ---------------------------------------------------------------------------
// Scan phase 3: block per (c,b); re-run chunk from carry-in; overwrite u
// bf16 pairs IN-PLACE with feature bf16 pairs: U16[t][2d]=bf16(h_r[d]),
// U16[t][2d+1]=bf16(h_i[d]). Each thread reads and writes the SAME 16 bytes
// (channels 4*tid..4*tid+3) -> no __syncthreads needed, pure streaming.
// ---------------------------------------------------------------------------
__global__ __launch_bounds__(256) void scan_p3_kernel(
    unsigned short* __restrict__ U16, const _Float16* __restrict__ NU,
    const float* __restrict__ theta_log, const float* __restrict__ chunkA) {
  const int c = blockIdx.x >> 2, b = blockIdx.x & 3;
  const int tid = threadIdx.x;
  float ct[4], st[4], hr[4], hi_[4];
#pragma unroll
  for (int dj = 0; dj < 4; ++dj) {
    int d = tid * 4 + dj;
    float th = expf(theta_log[d]);
    ct[dj] = cosf(th); st[dj] = sinf(th);
    const float* cp = chunkA + ((size_t)((c * 4 + b) * 1024) + d) * 4 + 2;
    hr[dj] = cp[0]; hi_[dj] = cp[1];
  }
  for (int i = 0; i < CL; ++i) {
    int t = (c * CL + i) * 4 + b;
    unsigned short* up = U16 + (size_t)t * 2048 + 8 * tid;
    bf16x8 uv = *(const bf16x8*)up;
    const _Float16* nup = NU + (size_t)t * 1024 + 4 * tid;
    bf16x8 fo;
#pragma unroll
    for (int dj = 0; dj < 4; ++dj) {
      float nu = (float)nup[dj];
      float lr = nu * ct[dj], li = nu * st[dj];
      float nhr = lr * hr[dj] - li * hi_[dj] + bf_to_f((unsigned short)uv[2 * dj]);
      float nhi = lr * hi_[dj] + li * hr[dj] + bf_to_f((unsigned short)uv[2 * dj + 1]);
      hr[dj] = nhr; hi_[dj] = nhi;
      fo[2 * dj] = (short)bf_rne(nhr);
      fo[2 * dj + 1] = (short)bf_rne(nhi);
    }
    *(bf16x8*)up = fo;
  }
}

// ---------------------------------------------------------------------------
// GEMM2 (MFMA): out[t][j] = F[t,:] . W2[j,:] + out_b[j], K=2048 bf16, BK=64.
// F = U16 after scan_p3 (contiguous rows, stride 2048 shorts).
// ---------------------------------------------------------------------------
__global__ __launch_bounds__(256) void gemm2_mfma(
    const unsigned short* __restrict__ F,
    const unsigned short* __restrict__ W2,
    const float* __restrict__ out_b,
    float* __restrict__ out) {
  __shared__ unsigned short As[8192];
  __shared__ unsigned short Bs[8192];
  const int tid = threadIdx.x;
  const int w = tid >> 6, l = tid & 63;
  const int q = l >> 4, ml = l & 15;
  const int m0 = blockIdx.y * 128;
  const int n0 = blockIdx.x * 128;
  const int wm = w & 1, wn = w >> 1;

  f32x4 acc[4][4] = {};

  for (int k0 = 0; k0 < 2048; k0 += 64) {
    __syncthreads();
#pragma unroll
    for (int h = 0; h < 2; ++h) {
      int kq = 2 * w + h;
      async16(F + (size_t)(m0 + l) * 2048 + k0 + kq * 8, &As[(kq * 128) * 8]);
      async16(F + (size_t)(m0 + 64 + l) * 2048 + k0 + kq * 8, &As[(kq * 128 + 64) * 8]);
      async16(W2 + (size_t)(n0 + l) * 2048 + k0 + kq * 8, &Bs[(kq * 128) * 8]);
      async16(W2 + (size_t)(n0 + 64 + l) * 2048 + k0 + kq * 8, &Bs[(kq * 128 + 64) * 8]);
    }
    __syncthreads();
#pragma unroll
    for (int s = 0; s < 2; ++s) {
      bf16x8 af[4], bfr[4];
#pragma unroll
      for (int i = 0; i < 4; ++i)
        af[i] = *(const bf16x8*)&As[(((s * 4 + q) * 128) + wm * 64 + i * 16 + ml) * 8];
#pragma unroll
      for (int j = 0; j < 4; ++j)
        bfr[j] = *(const bf16x8*)&Bs[(((s * 4 + q) * 128) + wn * 64 + j * 16 + ml) * 8];
#pragma unroll
      for (int i = 0; i < 4; ++i)
#pragma unroll
        for (int j = 0; j < 4; ++j)
          acc[i][j] = __builtin_amdgcn_mfma_f32_16x16x32_bf16(af[i], bfr[j], acc[i][j], 0, 0, 0);
    }
  }

#pragma unroll
  for (int j = 0; j < 4; ++j) {
    int col = n0 + wn * 64 + j * 16 + ml;
    float bias = out_b[col];
#pragma unroll
    for (int i = 0; i < 4; ++i) {
      int trow = m0 + wm * 64 + i * 16 + q * 4;
#pragma unroll
      for (int v = 0; v < 4; ++v) {
        int t = trow + v;
        out[((size_t)(t & 3) * NN + (t >> 2)) * DD + col] = acc[i][j][v] + bias;
      }
    }
  }
}

extern "C" void kernel_launch(void* const* d_in, const int* in_sizes, int n_in,
                              void* d_out, int out_size, void* d_ws, size_t ws_size,
                              hipStream_t stream) {
  const float* x         = (const float*)d_in[0];
  const float* theta_log = (const float*)d_in[1];
  const float* gamma_log = (const float*)d_in[2];
  const float* nu_w      = (const float*)d_in[3];
  const float* nu_b      = (const float*)d_in[4];
  const float* in_w      = (const float*)d_in[5];
  const float* in_b      = (const float*)d_in[6];
  const float* out_w     = (const float*)d_in[7];
  const float* out_b     = (const float*)d_in[8];
  float* out = (float*)d_out;

  // Workspace layout: 148,897,792 B total (round 0 proved ws_size >= 216 MB)
  char* base = (char*)d_ws;
  unsigned short* U16 = (unsigned short*)base;                 //  67,108,864
  _Float16*       NU  = (_Float16*)(base + 67108864);          //  33,554,432
  unsigned short* Abf = (unsigned short*)(base + 100663296);   //  33,554,432
  unsigned short* W1  = (unsigned short*)(base + 134217728);   //   6,291,456
  unsigned short* W2  = (unsigned short*)(base + 140509184);   //   4,194,304
  float*          chunkA = (float*)(base + 144703488);         //   4,194,304

  conv_x_kernel<<<(BB * NN * DD) / 256, 256, 0, stream>>>(x, Abf);
  conv_w1_kernel<<<(3072 * 1024) / 256, 256, 0, stream>>>(in_w, nu_w, W1);
  conv_w2_kernel<<<(1024 * 1024) / 256, 256, 0, stream>>>(out_w, W2);
  gemm1_mfma<<<dim3(3072 / 128, TT / 128), 256, 0, stream>>>(
      Abf, W1, in_b, nu_b, gamma_log, U16, NU);
  scan_p1_kernel<<<(NC * BB * DD) / 256, 256, 0, stream>>>(U16, NU, theta_log, chunkA);
  scan_p2_kernel<<<(BB * DD) / 256, 256, 0, stream>>>(chunkA);
  scan_p3_kernel<<<NC * BB, 256, 0, stream>>>(U16, NU, theta_log, chunkA);
  gemm2_mfma<<<dim3(1024 / 128, TT / 128), 256, 0, stream>>>(U16, W2, out_b, out);
}

// Round 5
// 563.995 us; speedup vs baseline: 4.2311x; 1.0052x over previous
//
#include <hip/hip_runtime.h>
#include <math.h>
#include <stdint.h>

#define BB 4
#define NN 4096
#define DD 1024
#define TT (BB * NN)          // 16384 tokens
#define NC 64                 // scan chunks
#define CL (NN / NC)          // 64 steps per chunk

typedef __attribute__((ext_vector_type(8))) short bf16x8;
typedef __attribute__((ext_vector_type(4))) float f32x4;

// bf16 round-to-nearest-even (returns top-16 bit pattern)
__device__ inline unsigned short bf_rne(float v) {
  union { float f; uint32_t u; } x; x.f = v;
  uint32_t r = x.u + 0x7fffu + ((x.u >> 16) & 1u);
  return (unsigned short)(r >> 16);
}
__device__ inline float bf_to_f(unsigned short h) {
  union { float f; uint32_t u; } x; x.u = ((uint32_t)h) << 16;
  return x.f;
}

// async global->LDS, 16 bytes per lane, deposits at (wave-uniform base + lane*16)
__device__ inline void async16(const void* g, void* l) {
  __builtin_amdgcn_global_load_lds(
      (const __attribute__((address_space(1))) uint32_t*)g,
      (__attribute__((address_space(3))) uint32_t*)l, 16, 0, 0);
}

// ---------------------------------------------------------------------------
// conv_x: x (b,n,d) fp32 -> Abf (t = n*4+b, 1024) bf16
// ---------------------------------------------------------------------------
__global__ __launch_bounds__(256) void conv_x_kernel(
    const float* __restrict__ x, unsigned short* __restrict__ Abf) {
  int idx = blockIdx.x * 256 + threadIdx.x;     // over BB*NN*DD
  int k = idx & 1023;
  int n = (idx >> 10) & 4095;
  int b = idx >> 22;
  Abf[(size_t)(n * 4 + b) * 1024 + k] = bf_rne(x[idx]);
}

// ---------------------------------------------------------------------------
// conv_w1: rows [in_w(2048); nu_w(1024)] (e,1024) fp32 -> W1 bf16
// ---------------------------------------------------------------------------
__global__ __launch_bounds__(256) void conv_w1_kernel(
    const float* __restrict__ in_w, const float* __restrict__ nu_w,
    unsigned short* __restrict__ W1) {
  int idx = blockIdx.x * 256 + threadIdx.x;     // over 3072*1024
  float v = (idx < 2048 * 1024) ? in_w[idx] : nu_w[idx - 2048 * 1024];
  W1[idx] = bf_rne(v);
}

// ---------------------------------------------------------------------------
// conv_w2: out_w (j, 2048) fp32 -> W2 (j, 2048) bf16, (r,i)-interleaved:
// W2[j][2d] = out_w[j][d], W2[j][2d+1] = out_w[j][1024+d]
// ---------------------------------------------------------------------------
__global__ __launch_bounds__(256) void conv_w2_kernel(
    const float* __restrict__ out_w, unsigned short* __restrict__ W2) {
  int idx = blockIdx.x * 256 + threadIdx.x;     // over 1024*1024
  int j = idx >> 10, d = idx & 1023;
  W2[(size_t)j * 2048 + 2 * d]     = bf_rne(out_w[(size_t)j * 2048 + d]);
  W2[(size_t)j * 2048 + 2 * d + 1] = bf_rne(out_w[(size_t)j * 2048 + 1024 + d]);
}

// ---------------------------------------------------------------------------
// GEMM1 (MFMA): z = Abf[t,:] . W1[e,:], K=1024 bf16. 128x128 tile, BK=64
// (16 K-iters, 32 MFMA per barrier), 4 waves, each 4x4 of 16x16x32 MFMA.
// __launch_bounds__(256,4): force <=128 regs/lane -> 4 blocks/CU so staging
// and compute phases of co-resident blocks overlap (round-4 post-mortem:
// phase-serialization at ~2 blocks/CU was the stall, not barrier count).
// Epilogue:
//   e < 2048 : U16[t,e]  = bf16( gamma[e>>1]*(z + in_b[e]) )   (u interleaved)
//   e >= 2048: NU[t,e']  = fp16( sigmoid(z + nu_b[e']) )
// ---------------------------------------------------------------------------
__global__ __launch_bounds__(256, 4) void gemm1_mfma(
    const unsigned short* __restrict__ A,
    const unsigned short* __restrict__ W1,
    const float* __restrict__ in_b, const float* __restrict__ nu_b,
    const float* __restrict__ gamma_log,
    unsigned short* __restrict__ U16, _Float16* __restrict__ NU) {
  __shared__ unsigned short As[8192];   // 16 KB
  __shared__ unsigned short Bs[8192];   // 16 KB
  const int tid = threadIdx.x;
  const int w = tid >> 6, l = tid & 63;
  const int q = l >> 4, ml = l & 15;
  const int m0 = blockIdx.y * 128;
  const int n0 = blockIdx.x * 128;
  const int wm = w & 1, wn = w >> 1;

  f32x4 acc[4][4] = {};

  for (int k0 = 0; k0 < 1024; k0 += 64) {
    __syncthreads();
#pragma unroll
    for (int h = 0; h < 2; ++h) {
      int kq = 2 * w + h;     // wave w stages kq slices 2w, 2w+1
      async16(A + (size_t)(m0 + l) * 1024 + k0 + kq * 8, &As[(kq * 128) * 8]);
      async16(A + (size_t)(m0 + 64 + l) * 1024 + k0 + kq * 8, &As[(kq * 128 + 64) * 8]);
      async16(W1 + (size_t)(n0 + l) * 1024 + k0 + kq * 8, &Bs[(kq * 128) * 8]);
      async16(W1 + (size_t)(n0 + 64 + l) * 1024 + k0 + kq * 8, &Bs[(kq * 128 + 64) * 8]);
    }
    __syncthreads();
#pragma unroll
    for (int s = 0; s < 2; ++s) {
      bf16x8 af[4], bfr[4];
#pragma unroll
      for (int i = 0; i < 4; ++i)
        af[i] = *(const bf16x8*)&As[(((s * 4 + q) * 128) + wm * 64 + i * 16 + ml) * 8];
#pragma unroll
      for (int j = 0; j < 4; ++j)
        bfr[j] = *(const bf16x8*)&Bs[(((s * 4 + q) * 128) + wn * 64 + j * 16 + ml) * 8];
#pragma unroll
      for (int i = 0; i < 4; ++i)
#pragma unroll
        for (int j = 0; j < 4; ++j)
          acc[i][j] = __builtin_amdgcn_mfma_f32_16x16x32_bf16(af[i], bfr[j], acc[i][j], 0, 0, 0);
    }
  }

  if (n0 < 2048) {   // u columns (block-uniform)
#pragma unroll
    for (int j = 0; j < 4; ++j) {
      int col = n0 + wn * 64 + j * 16 + ml;
      float bias = in_b[col];
      float gam = expf(gamma_log[col >> 1]);
#pragma unroll
      for (int i = 0; i < 4; ++i) {
        int trow = m0 + wm * 64 + i * 16 + q * 4;
#pragma unroll
        for (int v = 0; v < 4; ++v)
          U16[(size_t)(trow + v) * 2048 + col] = bf_rne(gam * (acc[i][j][v] + bias));
      }
    }
  } else {           // nu columns
#pragma unroll
    for (int j = 0; j < 4; ++j) {
      int col = n0 + wn * 64 + j * 16 + ml;
      int c2 = col - 2048;
      float bias = nu_b[c2];
#pragma unroll
      for (int i = 0; i < 4; ++i) {
        int trow = m0 + wm * 64 + i * 16 + q * 4;
#pragma unroll
        for (int v = 0; v < 4; ++v) {
          float z = acc[i][j][v] + bias;
          NU[(size_t)(trow + v) * 1024 + c2] = (_Float16)(1.f / (1.f + expf(-z)));
        }
      }
    }
  }
}

// ---------------------------------------------------------------------------
// Scan phase 1: per (chunk c, batch b, channel dch) local scan from h=0.
// Emits (A_r, A_i, hend_r, hend_i), A = prod of lambda over the chunk.
// ---------------------------------------------------------------------------
__global__ __launch_bounds__(256) void scan_p1_kernel(
    const unsigned short* __restrict__ U16, const _Float16* __restrict__ NU,
    const float* __restrict__ theta_log,
    float* __restrict__ chunkA) {
  int s = blockIdx.x * 256 + threadIdx.x;   // ((c*BB)+b)*DD + dch
  int dch = s & (DD - 1);
  int b = (s >> 10) & (BB - 1);
  int c = s >> 12;
  float theta = expf(theta_log[dch]);
  float ct = cosf(theta), st = sinf(theta);
  float hr = 0.f, hi = 0.f, Ar = 1.f, Ai = 0.f;
  for (int i = 0; i < CL; ++i) {
    int t = (c * CL + i) * 4 + b;
    ushort2 up = *(const ushort2*)(U16 + (size_t)t * 2048 + 2 * dch);
    float ur = bf_to_f(up.x), ui = bf_to_f(up.y);
    float nu = (float)NU[(size_t)t * 1024 + dch];
    float lr = nu * ct, li = nu * st;
    float hr2 = lr * hr - li * hi + ur;
    float hi2 = lr * hi + li * hr + ui;
    hr = hr2; hi = hi2;
    float Ar2 = lr * Ar - li * Ai;
    float Ai2 = lr * Ai + li * Ar;
    Ar = Ar2; Ai = Ai2;
  }
  float4 o = {Ar, Ai, hr, hi};
  *(float4*)(chunkA + (size_t)s * 4) = o;
}

// ---------------------------------------------------------------------------
// Scan phase 2: compose NC chunk summaries per channel; overwrite each
// entry's (z,w) slots in-place with that chunk's carry-in state.
// ---------------------------------------------------------------------------
__global__ __launch_bounds__(256) void scan_p2_kernel(
    float* __restrict__ chunkA) {
  int qx = blockIdx.x * 256 + threadIdx.x;   // b*DD + dch
  int dch = qx & (DD - 1);
  int b = qx >> 10;
  float cr = 0.f, ci = 0.f;
  for (int c = 0; c < NC; ++c) {
    size_t idx = ((size_t)(c * BB + b) * DD + dch) * 4;
    float4 v = *(const float4*)(chunkA + idx);
    float2 wv = {cr, ci};
    *(float2*)(chunkA + idx + 2) = wv;      // carry-in for chunk c
    float nr = v.x * cr - v.y * ci + v.z;
    float ni = v.x * ci + v.y * cr + v.w;
    cr = nr; ci = ni;
  }
}

// ---------------------------------------------------------------------------
// Scan phase 3: block per (c,b); re-run chunk from carry-in; overwrite u
// bf16 pairs IN-PLACE with feature bf16 pairs: U16[t][2d]=bf16(h_r[d]),
// U16[t][2d+1]=bf16(h_i[d]). Each thread reads and writes the SAME 16 bytes
// (channels 4*tid..4*tid+3) -> no __syncthreads needed, pure streaming.
// ---------------------------------------------------------------------------
__global__ __launch_bounds__(256) void scan_p3_kernel(
    unsigned short* __restrict__ U16, const _Float16* __restrict__ NU,
    const float* __restrict__ theta_log, const float* __restrict__ chunkA) {
  const int c = blockIdx.x >> 2, b = blockIdx.x & 3;
  const int tid = threadIdx.x;
  float ct[4], st[4], hr[4], hi_[4];
#pragma unroll
  for (int dj = 0; dj < 4; ++dj) {
    int d = tid * 4 + dj;
    float th = expf(theta_log[d]);
    ct[dj] = cosf(th); st[dj] = sinf(th);
    const float* cp = chunkA + ((size_t)((c * 4 + b) * 1024) + d) * 4 + 2;
    hr[dj] = cp[0]; hi_[dj] = cp[1];
  }
  for (int i = 0; i < CL; ++i) {
    int t = (c * CL + i) * 4 + b;
    unsigned short* up = U16 + (size_t)t * 2048 + 8 * tid;
    bf16x8 uv = *(const bf16x8*)up;
    const _Float16* nup = NU + (size_t)t * 1024 + 4 * tid;
    bf16x8 fo;
#pragma unroll
    for (int dj = 0; dj < 4; ++dj) {
      float nu = (float)nup[dj];
      float lr = nu * ct[dj], li = nu * st[dj];
      float nhr = lr * hr[dj] - li * hi_[dj] + bf_to_f((unsigned short)uv[2 * dj]);
      float nhi = lr * hi_[dj] + li * hr[dj] + bf_to_f((unsigned short)uv[2 * dj + 1]);
      hr[dj] = nhr; hi_[dj] = nhi;
      fo[2 * dj] = (short)bf_rne(nhr);
      fo[2 * dj + 1] = (short)bf_rne(nhi);
    }
    *(bf16x8*)up = fo;
  }
}

// ---------------------------------------------------------------------------
// GEMM2 (MFMA): out[t][j] = F[t,:] . W2[j,:] + out_b[j], K=2048 bf16, BK=64.
// F = U16 after scan_p3 (contiguous rows, stride 2048 shorts).
// __launch_bounds__(256,4) as in gemm1.
// ---------------------------------------------------------------------------
__global__ __launch_bounds__(256, 4) void gemm2_mfma(
    const unsigned short* __restrict__ F,
    const unsigned short* __restrict__ W2,
    const float* __restrict__ out_b,
    float* __restrict__ out) {
  __shared__ unsigned short As[8192];
  __shared__ unsigned short Bs[8192];
  const int tid = threadIdx.x;
  const int w = tid >> 6, l = tid & 63;
  const int q = l >> 4, ml = l & 15;
  const int m0 = blockIdx.y * 128;
  const int n0 = blockIdx.x * 128;
  const int wm = w & 1, wn = w >> 1;

  f32x4 acc[4][4] = {};

  for (int k0 = 0; k0 < 2048; k0 += 64) {
    __syncthreads();
#pragma unroll
    for (int h = 0; h < 2; ++h) {
      int kq = 2 * w + h;
      async16(F + (size_t)(m0 + l) * 2048 + k0 + kq * 8, &As[(kq * 128) * 8]);
      async16(F + (size_t)(m0 + 64 + l) * 2048 + k0 + kq * 8, &As[(kq * 128 + 64) * 8]);
      async16(W2 + (size_t)(n0 + l) * 2048 + k0 + kq * 8, &Bs[(kq * 128) * 8]);
      async16(W2 + (size_t)(n0 + 64 + l) * 2048 + k0 + kq * 8, &Bs[(kq * 128 + 64) * 8]);
    }
    __syncthreads();
#pragma unroll
    for (int s = 0; s < 2; ++s) {
      bf16x8 af[4], bfr[4];
#pragma unroll
      for (int i = 0; i < 4; ++i)
        af[i] = *(const bf16x8*)&As[(((s * 4 + q) * 128) + wm * 64 + i * 16 + ml) * 8];
#pragma unroll
      for (int j = 0; j < 4; ++j)
        bfr[j] = *(const bf16x8*)&Bs[(((s * 4 + q) * 128) + wn * 64 + j * 16 + ml) * 8];
#pragma unroll
      for (int i = 0; i < 4; ++i)
#pragma unroll
        for (int j = 0; j < 4; ++j)
          acc[i][j] = __builtin_amdgcn_mfma_f32_16x16x32_bf16(af[i], bfr[j], acc[i][j], 0, 0, 0);
    }
  }

#pragma unroll
  for (int j = 0; j < 4; ++j) {
    int col = n0 + wn * 64 + j * 16 + ml;
    float bias = out_b[col];
#pragma unroll
    for (int i = 0; i < 4; ++i) {
      int trow = m0 + wm * 64 + i * 16 + q * 4;
#pragma unroll
      for (int v = 0; v < 4; ++v) {
        int t = trow + v;
        out[((size_t)(t & 3) * NN + (t >> 2)) * DD + col] = acc[i][j][v] + bias;
      }
    }
  }
}

extern "C" void kernel_launch(void* const* d_in, const int* in_sizes, int n_in,
                              void* d_out, int out_size, void* d_ws, size_t ws_size,
                              hipStream_t stream) {
  const float* x         = (const float*)d_in[0];
  const float* theta_log = (const float*)d_in[1];
  const float* gamma_log = (const float*)d_in[2];
  const float* nu_w      = (const float*)d_in[3];
  const float* nu_b      = (const float*)d_in[4];
  const float* in_w      = (const float*)d_in[5];
  const float* in_b      = (const float*)d_in[6];
  const float* out_w     = (const float*)d_in[7];
  const float* out_b     = (const float*)d_in[8];
  float* out = (float*)d_out;

  // Workspace layout: 148,897,792 B total (round 0 proved ws_size >= 216 MB)
  char* base = (char*)d_ws;
  unsigned short* U16 = (unsigned short*)base;                 //  67,108,864
  _Float16*       NU  = (_Float16*)(base + 67108864);          //  33,554,432
  unsigned short* Abf = (unsigned short*)(base + 100663296);   //  33,554,432
  unsigned short* W1  = (unsigned short*)(base + 134217728);   //   6,291,456
  unsigned short* W2  = (unsigned short*)(base + 140509184);   //   4,194,304
  float*          chunkA = (float*)(base + 144703488);         //   4,194,304

  conv_x_kernel<<<(BB * NN * DD) / 256, 256, 0, stream>>>(x, Abf);
  conv_w1_kernel<<<(3072 * 1024) / 256, 256, 0, stream>>>(in_w, nu_w, W1);
  conv_w2_kernel<<<(1024 * 1024) / 256, 256, 0, stream>>>(out_w, W2);
  gemm1_mfma<<<dim3(3072 / 128, TT / 128), 256, 0, stream>>>(
      Abf, W1, in_b, nu_b, gamma_log, U16, NU);
  scan_p1_kernel<<<(NC * BB * DD) / 256, 256, 0, stream>>>(U16, NU, theta_log, chunkA);
  scan_p2_kernel<<<(BB * DD) / 256, 256, 0, stream>>>(chunkA);
  scan_p3_kernel<<<NC * BB, 256, 0, stream>>>(U16, NU, theta_log, chunkA);
  gemm2_mfma<<<dim3(1024 / 128, TT / 128), 256, 0, stream>>>(U16, W2, out_b, out);
}